// Round 1
// baseline (9398.316 us; speedup 1.0000x reference)
//
#include <hip/hip_runtime.h>

#define D 128
#define TILE_ROWS 32

// ---------------------------------------------------------------------------
// Edge scatter: agg[dst] += X[src]  (agg pre-initialized with X for the +x)
// 32 threads per edge, float4 per thread, 4 f32 HW atomics.
// ---------------------------------------------------------------------------
__global__ __launch_bounds__(256) void scatter_add_kernel(
    const float* __restrict__ X, const int* __restrict__ ei,
    float* __restrict__ agg, int n_edges) {
  long long t = (long long)blockIdx.x * blockDim.x + threadIdx.x;
  int e = (int)(t >> 5);
  if (e >= n_edges) return;
  int c = ((int)t & 31) << 2;
  int s = ei[e];
  int d = ei[n_edges + e];
  const float4 v = *reinterpret_cast<const float4*>(X + (size_t)s * D + c);
  float* p = agg + (size_t)d * D + c;
  unsafeAtomicAdd(p + 0, v.x);
  unsafeAtomicAdd(p + 1, v.y);
  unsafeAtomicAdd(p + 2, v.z);
  unsafeAtomicAdd(p + 3, v.w);
}

// ---------------------------------------------------------------------------
// out = [relu](S @ W + b), S: n_rows x 128, W: 128x128 (row-major fan_in x
// fan_out), b: 128. W staged in LDS (64KB); each thread: 4 rows x 4 cols.
// Requires n_rows % 32 == 0 (100000 % 32 == 0).
// ---------------------------------------------------------------------------
template <int RELU>
__global__ __launch_bounds__(256) void mlp_kernel(
    const float* __restrict__ S, const float* __restrict__ W,
    const float* __restrict__ bias, float* __restrict__ out, int n_rows) {
  __shared__ float wl[D * D];
  for (int i = threadIdx.x * 4; i < D * D; i += 256 * 4) {
    *reinterpret_cast<float4*>(wl + i) = *reinterpret_cast<const float4*>(W + i);
  }
  __syncthreads();

  const int cg = (threadIdx.x & 31) * 4;   // 4 output cols
  const int rg = (threadIdx.x >> 5) * 4;   // 4 rows within tile
  const float4 bv = *reinterpret_cast<const float4*>(bias + cg);

  for (int row0 = blockIdx.x * TILE_ROWS; row0 < n_rows;
       row0 += gridDim.x * TILE_ROWS) {
    const int r = row0 + rg;
    float acc[4][4];
#pragma unroll
    for (int i = 0; i < 4; ++i)
#pragma unroll
      for (int j = 0; j < 4; ++j) acc[i][j] = 0.0f;

#pragma unroll 4
    for (int k4 = 0; k4 < D / 4; ++k4) {
      float4 xv[4];
#pragma unroll
      for (int i = 0; i < 4; ++i)
        xv[i] = *reinterpret_cast<const float4*>(S + (size_t)(r + i) * D + k4 * 4);
#pragma unroll
      for (int kk = 0; kk < 4; ++kk) {
        const float4 wv =
            *reinterpret_cast<const float4*>(wl + (k4 * 4 + kk) * D + cg);
#pragma unroll
        for (int i = 0; i < 4; ++i) {
          const float xs = (kk == 0) ? xv[i].x
                         : (kk == 1) ? xv[i].y
                         : (kk == 2) ? xv[i].z
                                     : xv[i].w;
          acc[i][0] = fmaf(xs, wv.x, acc[i][0]);
          acc[i][1] = fmaf(xs, wv.y, acc[i][1]);
          acc[i][2] = fmaf(xs, wv.z, acc[i][2]);
          acc[i][3] = fmaf(xs, wv.w, acc[i][3]);
        }
      }
    }

#pragma unroll
    for (int i = 0; i < 4; ++i) {
      float4 o;
      o.x = acc[i][0] + bv.x;
      o.y = acc[i][1] + bv.y;
      o.z = acc[i][2] + bv.z;
      o.w = acc[i][3] + bv.w;
      if (RELU) {
        o.x = fmaxf(o.x, 0.0f);
        o.y = fmaxf(o.y, 0.0f);
        o.z = fmaxf(o.z, 0.0f);
        o.w = fmaxf(o.w, 0.0f);
      }
      *reinterpret_cast<float4*>(out + (size_t)(r + i) * D + cg) = o;
    }
  }
}

// ---------------------------------------------------------------------------
// Global mean pool: atomic accumulate sums + counts, then normalize.
// ---------------------------------------------------------------------------
__global__ __launch_bounds__(256) void pool_accum_kernel(
    const float* __restrict__ H, const int* __restrict__ batch,
    float* __restrict__ out, float* __restrict__ counts, int n_nodes) {
  long long t = (long long)blockIdx.x * blockDim.x + threadIdx.x;
  int n = (int)(t >> 5);
  if (n >= n_nodes) return;
  int c = ((int)t & 31) << 2;
  int g = batch[n];
  const float4 v = *reinterpret_cast<const float4*>(H + (size_t)n * D + c);
  float* p = out + (size_t)g * D + c;
  unsafeAtomicAdd(p + 0, v.x);
  unsafeAtomicAdd(p + 1, v.y);
  unsafeAtomicAdd(p + 2, v.z);
  unsafeAtomicAdd(p + 3, v.w);
  if (c == 0) unsafeAtomicAdd(counts + g, 1.0f);
}

__global__ __launch_bounds__(256) void pool_norm_kernel(
    float* __restrict__ out, const float* __restrict__ counts, int n) {
  int i = blockIdx.x * blockDim.x + threadIdx.x;
  if (i >= n) return;
  float cnt = counts[i / D];
  out[i] = out[i] / fmaxf(cnt, 1.0f);
}

// ---------------------------------------------------------------------------
extern "C" void kernel_launch(void* const* d_in, const int* in_sizes, int n_in,
                              void* d_out, int out_size, void* d_ws,
                              size_t ws_size, hipStream_t stream) {
  const float* x = (const float*)d_in[0];
  const int* ei = (const int*)d_in[1];
  const int* batch = (const int*)d_in[2];
  const float* w1_1 = (const float*)d_in[3];
  const float* b1_1 = (const float*)d_in[4];
  const float* w2_1 = (const float*)d_in[5];
  const float* b2_1 = (const float*)d_in[6];
  const float* w1_2 = (const float*)d_in[7];
  const float* b1_2 = (const float*)d_in[8];
  const float* w2_2 = (const float*)d_in[9];
  const float* b2_2 = (const float*)d_in[10];
  const float* w1_3 = (const float*)d_in[11];
  const float* b1_3 = (const float*)d_in[12];
  const float* w2_3 = (const float*)d_in[13];
  const float* b2_3 = (const float*)d_in[14];

  const int n_nodes = in_sizes[2];
  const int n_edges = in_sizes[1] / 2;
  const int n_graphs = out_size / D;

  const size_t matBytes = (size_t)n_nodes * D * sizeof(float);
  float* buf0 = (float*)d_ws;
  float* buf1 = (float*)((char*)d_ws + matBytes);
  float* buf2 = (float*)((char*)d_ws + 2 * matBytes);
  float* counts = (float*)((char*)d_ws + 3 * matBytes);

  const dim3 blk(256);
  const int scatter_blocks = (int)(((long long)n_edges * 32 + 255) / 256);
  const int pool_blocks = (int)(((long long)n_nodes * 32 + 255) / 256);
  const int mlp_grid = 512;  // 2 blocks/CU (64KB LDS each), grid-stride tiles

  // ---- layer 1: in = x ----
  hipMemcpyAsync(buf0, x, matBytes, hipMemcpyDeviceToDevice, stream);  // agg = x
  scatter_add_kernel<<<scatter_blocks, blk, 0, stream>>>(x, ei, buf0, n_edges);
  mlp_kernel<1><<<mlp_grid, blk, 0, stream>>>(buf0, w1_1, b1_1, buf1, n_nodes);
  mlp_kernel<1><<<mlp_grid, blk, 0, stream>>>(buf1, w2_1, b2_1, buf2, n_nodes);

  // ---- layer 2: in = buf2 ----
  hipMemcpyAsync(buf0, buf2, matBytes, hipMemcpyDeviceToDevice, stream);
  scatter_add_kernel<<<scatter_blocks, blk, 0, stream>>>(buf2, ei, buf0, n_edges);
  mlp_kernel<1><<<mlp_grid, blk, 0, stream>>>(buf0, w1_2, b1_2, buf1, n_nodes);
  mlp_kernel<1><<<mlp_grid, blk, 0, stream>>>(buf1, w2_2, b2_2, buf0, n_nodes);

  // ---- layer 3: in = buf0 ----
  hipMemcpyAsync(buf2, buf0, matBytes, hipMemcpyDeviceToDevice, stream);
  scatter_add_kernel<<<scatter_blocks, blk, 0, stream>>>(buf0, ei, buf2, n_edges);
  mlp_kernel<1><<<mlp_grid, blk, 0, stream>>>(buf2, w1_3, b1_3, buf1, n_nodes);
  mlp_kernel<0><<<mlp_grid, blk, 0, stream>>>(buf1, w2_3, b2_3, buf2, n_nodes);

  // ---- global mean pool ----
  hipMemsetAsync(d_out, 0, (size_t)out_size * sizeof(float), stream);
  hipMemsetAsync(counts, 0, (size_t)n_graphs * sizeof(float), stream);
  pool_accum_kernel<<<pool_blocks, blk, 0, stream>>>(buf2, batch, (float*)d_out,
                                                     counts, n_nodes);
  pool_norm_kernel<<<(out_size + 255) / 256, blk, 0, stream>>>(
      (float*)d_out, counts, out_size);
}

// Round 2
// 984.065 us; speedup vs baseline: 9.5505x; 9.5505x over previous
//
#include <hip/hip_runtime.h>

#define D 128
#define TILE_ROWS 32
#define SCAN_CHUNK 1024

// ---------------------------------------------------------------------------
// CSR build: histogram -> 2-level exclusive scan -> fill
// ---------------------------------------------------------------------------
__global__ __launch_bounds__(256) void hist_kernel(
    const int* __restrict__ dst, int* __restrict__ cnt, int n_edges) {
  int e = blockIdx.x * 256 + threadIdx.x;
  if (e < n_edges) atomicAdd(&cnt[dst[e]], 1);
}

// Per-chunk exclusive scan; writes within-chunk exclusive prefix to rowptr,
// chunk total to chunkSums. CHUNK=1024, 256 threads x 4 elements.
__global__ __launch_bounds__(256) void scanA_kernel(
    const int* __restrict__ cnt, int* __restrict__ rowptr,
    int* __restrict__ chunkSums, int n) {
  __shared__ int lds[256];
  const int t = threadIdx.x;
  const int idx = blockIdx.x * SCAN_CHUNK + t * 4;
  int4 v = make_int4(0, 0, 0, 0);
  if (idx < n) v = *reinterpret_cast<const int4*>(cnt + idx);  // n % 4 == 0
  const int s = v.x + v.y + v.z + v.w;
  lds[t] = s;
  __syncthreads();
#pragma unroll
  for (int off = 1; off < 256; off <<= 1) {
    int p = 0;
    if (t >= off) p = lds[t - off];
    __syncthreads();
    lds[t] += p;
    __syncthreads();
  }
  const int excl = lds[t] - s;  // exclusive prefix of this thread's 4 elems
  if (idx < n) {
    int4 o;
    o.x = excl;
    o.y = excl + v.x;
    o.z = o.y + v.y;
    o.w = o.z + v.z;
    *reinterpret_cast<int4*>(rowptr + idx) = o;
  }
  if (t == 255) chunkSums[blockIdx.x] = lds[255];
}

// Single-block exclusive scan of chunk sums (n_chunks <= 256).
__global__ __launch_bounds__(256) void scanB_kernel(int* __restrict__ chunkSums,
                                                    int n_chunks) {
  __shared__ int lds[256];
  const int t = threadIdx.x;
  const int v = (t < n_chunks) ? chunkSums[t] : 0;
  lds[t] = v;
  __syncthreads();
#pragma unroll
  for (int off = 1; off < 256; off <<= 1) {
    int p = 0;
    if (t >= off) p = lds[t - off];
    __syncthreads();
    lds[t] += p;
    __syncthreads();
  }
  if (t < n_chunks) chunkSums[t] = lds[t] - v;  // exclusive
}

// Add chunk offsets, finalize rowptr, init fill cursors.
__global__ __launch_bounds__(256) void scanC_kernel(
    int* __restrict__ rowptr, const int* __restrict__ chunkSums,
    int* __restrict__ cursor, int n_nodes, int n_edges) {
  int i = blockIdx.x * 256 + threadIdx.x;
  if (i < n_nodes) {
    int v = rowptr[i] + chunkSums[i / SCAN_CHUNK];
    rowptr[i] = v;
    cursor[i] = v;
  }
  if (i == n_nodes) rowptr[n_nodes] = n_edges;
}

__global__ __launch_bounds__(256) void fill_kernel(
    const int* __restrict__ src, const int* __restrict__ dst,
    int* __restrict__ cursor, int* __restrict__ col, int n_edges) {
  int e = blockIdx.x * 256 + threadIdx.x;
  if (e < n_edges) {
    int d = dst[e];
    int pos = atomicAdd(&cursor[d], 1);
    col[pos] = src[e];
  }
}

// ---------------------------------------------------------------------------
// Gather aggregation: out[n] = X[n] + sum_{j in in-edges(n)} X[col[j]]
// 32 threads per node, float4 per lane (512B contiguous per row).
// ---------------------------------------------------------------------------
__global__ __launch_bounds__(256) void gather_kernel(
    const float* __restrict__ X, const int* __restrict__ rowptr,
    const int* __restrict__ col, float* __restrict__ out, int n_nodes) {
  int g = (blockIdx.x * 256 + threadIdx.x) >> 5;  // node
  if (g >= n_nodes) return;
  const int c4 = threadIdx.x & 31;  // float4 index within row
  const float4* Xv = reinterpret_cast<const float4*>(X);
  float4 acc = Xv[(size_t)g * 32 + c4];  // self term (eps = 0)
  const int beg = rowptr[g], end = rowptr[g + 1];
  for (int j = beg; j < end; ++j) {
    const int s = col[j];
    const float4 v = Xv[(size_t)s * 32 + c4];
    acc.x += v.x;
    acc.y += v.y;
    acc.z += v.z;
    acc.w += v.w;
  }
  reinterpret_cast<float4*>(out)[(size_t)g * 32 + c4] = acc;
}

// ---------------------------------------------------------------------------
// out = [relu](S @ W + b); W staged in LDS; thread tile 4 rows x 4 cols.
// ---------------------------------------------------------------------------
template <int RELU>
__global__ __launch_bounds__(256) void mlp_kernel(
    const float* __restrict__ S, const float* __restrict__ W,
    const float* __restrict__ bias, float* __restrict__ out, int n_rows) {
  __shared__ float wl[D * D];
  for (int i = threadIdx.x * 4; i < D * D; i += 256 * 4) {
    *reinterpret_cast<float4*>(wl + i) = *reinterpret_cast<const float4*>(W + i);
  }
  __syncthreads();

  const int cg = (threadIdx.x & 31) * 4;
  const int rg = (threadIdx.x >> 5) * 4;
  const float4 bv = *reinterpret_cast<const float4*>(bias + cg);

  for (int row0 = blockIdx.x * TILE_ROWS; row0 < n_rows;
       row0 += gridDim.x * TILE_ROWS) {
    const int r = row0 + rg;
    float acc[4][4];
#pragma unroll
    for (int i = 0; i < 4; ++i)
#pragma unroll
      for (int j = 0; j < 4; ++j) acc[i][j] = 0.0f;

#pragma unroll 4
    for (int k4 = 0; k4 < D / 4; ++k4) {
      float4 xv[4];
#pragma unroll
      for (int i = 0; i < 4; ++i)
        xv[i] = *reinterpret_cast<const float4*>(S + (size_t)(r + i) * D + k4 * 4);
#pragma unroll
      for (int kk = 0; kk < 4; ++kk) {
        const float4 wv =
            *reinterpret_cast<const float4*>(wl + (k4 * 4 + kk) * D + cg);
#pragma unroll
        for (int i = 0; i < 4; ++i) {
          const float xs = (kk == 0) ? xv[i].x
                         : (kk == 1) ? xv[i].y
                         : (kk == 2) ? xv[i].z
                                     : xv[i].w;
          acc[i][0] = fmaf(xs, wv.x, acc[i][0]);
          acc[i][1] = fmaf(xs, wv.y, acc[i][1]);
          acc[i][2] = fmaf(xs, wv.z, acc[i][2]);
          acc[i][3] = fmaf(xs, wv.w, acc[i][3]);
        }
      }
    }

#pragma unroll
    for (int i = 0; i < 4; ++i) {
      float4 o;
      o.x = acc[i][0] + bv.x;
      o.y = acc[i][1] + bv.y;
      o.z = acc[i][2] + bv.z;
      o.w = acc[i][3] + bv.w;
      if (RELU) {
        o.x = fmaxf(o.x, 0.0f);
        o.y = fmaxf(o.y, 0.0f);
        o.z = fmaxf(o.z, 0.0f);
        o.w = fmaxf(o.w, 0.0f);
      }
      *reinterpret_cast<float4*>(out + (size_t)(r + i) * D + cg) = o;
    }
  }
}

// ---------------------------------------------------------------------------
// Global mean pool. `batch` is sorted: run-length accumulate per 32-lane
// group, one atomic flush per graph-run.
// ---------------------------------------------------------------------------
#define POOL_NODES_PER_GROUP 128

__global__ __launch_bounds__(256) void pool_kernel(
    const float* __restrict__ H, const int* __restrict__ batch,
    float* __restrict__ sums, float* __restrict__ counts, int n_nodes) {
  const int group = (blockIdx.x * 256 + threadIdx.x) >> 5;
  const int lane = threadIdx.x & 31;
  const int n0 = group * POOL_NODES_PER_GROUP;
  if (n0 >= n_nodes) return;
  const int n1 = min(n0 + POOL_NODES_PER_GROUP, n_nodes);
  const float4* Hv = reinterpret_cast<const float4*>(H);

  float4 acc = make_float4(0.f, 0.f, 0.f, 0.f);
  int cur = batch[n0];
  int runlen = 0;
  for (int n = n0; n < n1; ++n) {
    const int g = batch[n];
    if (g != cur) {
      float* p = sums + (size_t)cur * D + lane * 4;
      unsafeAtomicAdd(p + 0, acc.x);
      unsafeAtomicAdd(p + 1, acc.y);
      unsafeAtomicAdd(p + 2, acc.z);
      unsafeAtomicAdd(p + 3, acc.w);
      if (lane == 0) unsafeAtomicAdd(counts + cur, (float)runlen);
      acc = make_float4(0.f, 0.f, 0.f, 0.f);
      cur = g;
      runlen = 0;
    }
    const float4 v = Hv[(size_t)n * 32 + lane];
    acc.x += v.x;
    acc.y += v.y;
    acc.z += v.z;
    acc.w += v.w;
    ++runlen;
  }
  float* p = sums + (size_t)cur * D + lane * 4;
  unsafeAtomicAdd(p + 0, acc.x);
  unsafeAtomicAdd(p + 1, acc.y);
  unsafeAtomicAdd(p + 2, acc.z);
  unsafeAtomicAdd(p + 3, acc.w);
  if (lane == 0) unsafeAtomicAdd(counts + cur, (float)runlen);
}

__global__ __launch_bounds__(256) void pool_norm_kernel(
    float* __restrict__ out, const float* __restrict__ counts, int n) {
  int i = blockIdx.x * 256 + threadIdx.x;
  if (i >= n) return;
  float cnt = counts[i / D];
  out[i] = out[i] / fmaxf(cnt, 1.0f);
}

// ---------------------------------------------------------------------------
extern "C" void kernel_launch(void* const* d_in, const int* in_sizes, int n_in,
                              void* d_out, int out_size, void* d_ws,
                              size_t ws_size, hipStream_t stream) {
  const float* x = (const float*)d_in[0];
  const int* ei = (const int*)d_in[1];
  const int* batch = (const int*)d_in[2];
  const float* w1_1 = (const float*)d_in[3];
  const float* b1_1 = (const float*)d_in[4];
  const float* w2_1 = (const float*)d_in[5];
  const float* b2_1 = (const float*)d_in[6];
  const float* w1_2 = (const float*)d_in[7];
  const float* b1_2 = (const float*)d_in[8];
  const float* w2_2 = (const float*)d_in[9];
  const float* b2_2 = (const float*)d_in[10];
  const float* w1_3 = (const float*)d_in[11];
  const float* b1_3 = (const float*)d_in[12];
  const float* w2_3 = (const float*)d_in[13];
  const float* b2_3 = (const float*)d_in[14];

  const int n_nodes = in_sizes[2];
  const int n_edges = in_sizes[1] / 2;
  const int n_graphs = out_size / D;
  const int* src = ei;
  const int* dst = ei + n_edges;

  const size_t matBytes = (size_t)n_nodes * D * sizeof(float);
  float* b0 = (float*)d_ws;
  float* b1 = (float*)((char*)d_ws + matBytes);
  int* rowptr = (int*)((char*)d_ws + 2 * matBytes);
  int* cursor = rowptr + (n_nodes + 1);
  int* col = cursor + n_nodes;
  int* chunkSums = col + n_edges;
  float* counts = (float*)(chunkSums + 256);

  const dim3 blk(256);
  const int edge_blocks = (n_edges + 255) / 256;
  const int n_chunks = (n_nodes + SCAN_CHUNK - 1) / SCAN_CHUNK;
  const int gather_blocks = (int)(((long long)n_nodes * 32 + 255) / 256);
  const int pool_groups = (n_nodes + POOL_NODES_PER_GROUP - 1) / POOL_NODES_PER_GROUP;
  const int pool_blocks = (pool_groups * 32 + 255) / 256;
  const int mlp_grid = 512;

  // ---- CSR build (by dst) ----
  hipMemsetAsync(cursor, 0, (size_t)n_nodes * sizeof(int), stream);
  hist_kernel<<<edge_blocks, blk, 0, stream>>>(dst, cursor, n_edges);
  scanA_kernel<<<n_chunks, blk, 0, stream>>>(cursor, rowptr, chunkSums, n_nodes);
  scanB_kernel<<<1, blk, 0, stream>>>(chunkSums, n_chunks);
  scanC_kernel<<<(n_nodes + 256) / 256, blk, 0, stream>>>(rowptr, chunkSums,
                                                          cursor, n_nodes, n_edges);
  fill_kernel<<<edge_blocks, blk, 0, stream>>>(src, dst, cursor, col, n_edges);

  // ---- layer 1 ----
  gather_kernel<<<gather_blocks, blk, 0, stream>>>(x, rowptr, col, b0, n_nodes);
  mlp_kernel<1><<<mlp_grid, blk, 0, stream>>>(b0, w1_1, b1_1, b1, n_nodes);
  mlp_kernel<1><<<mlp_grid, blk, 0, stream>>>(b1, w2_1, b2_1, b0, n_nodes);
  // ---- layer 2 ----
  gather_kernel<<<gather_blocks, blk, 0, stream>>>(b0, rowptr, col, b1, n_nodes);
  mlp_kernel<1><<<mlp_grid, blk, 0, stream>>>(b1, w1_2, b1_2, b0, n_nodes);
  mlp_kernel<1><<<mlp_grid, blk, 0, stream>>>(b0, w2_2, b2_2, b1, n_nodes);
  // ---- layer 3 ----
  gather_kernel<<<gather_blocks, blk, 0, stream>>>(b1, rowptr, col, b0, n_nodes);
  mlp_kernel<1><<<mlp_grid, blk, 0, stream>>>(b0, w1_3, b1_3, b1, n_nodes);
  mlp_kernel<0><<<mlp_grid, blk, 0, stream>>>(b1, w2_3, b2_3, b0, n_nodes);

  // ---- global mean pool ----
  hipMemsetAsync(d_out, 0, (size_t)out_size * sizeof(float), stream);
  hipMemsetAsync(counts, 0, (size_t)n_graphs * sizeof(float), stream);
  pool_kernel<<<pool_blocks, blk, 0, stream>>>(b0, batch, (float*)d_out, counts,
                                               n_nodes);
  pool_norm_kernel<<<(out_size + 255) / 256, blk, 0, stream>>>((float*)d_out,
                                                               counts, out_size);
}

// Round 3
// 664.718 us; speedup vs baseline: 14.1388x; 1.4804x over previous
//
#include <hip/hip_runtime.h>

#define D 128
#define SCAN_CHUNK 1024

typedef __attribute__((ext_vector_type(8))) short bf16x8;
typedef __attribute__((ext_vector_type(16))) float f32x16;

__device__ inline float b2f(unsigned int hi16_as_lo) {
  union { unsigned int u; float f; } v;
  v.u = hi16_as_lo;
  return v.f;
}
__device__ inline unsigned short f2b(float f) {  // RNE f32 -> bf16
  union { float f; unsigned int u; } v;
  v.f = f;
  unsigned int r = v.u + 0x7FFFu + ((v.u >> 16) & 1u);
  return (unsigned short)(r >> 16);
}

// ---------------------------------------------------------------------------
// f32 -> bf16 convert (8 elems/thread)
// ---------------------------------------------------------------------------
__global__ __launch_bounds__(256) void convert_kernel(
    const float* __restrict__ in, unsigned short* __restrict__ out, int n8) {
  int i = blockIdx.x * 256 + threadIdx.x;
  if (i >= n8) return;
  const float4 a = *reinterpret_cast<const float4*>(in + (size_t)i * 8);
  const float4 b = *reinterpret_cast<const float4*>(in + (size_t)i * 8 + 4);
  unsigned short o[8] = {f2b(a.x), f2b(a.y), f2b(a.z), f2b(a.w),
                         f2b(b.x), f2b(b.y), f2b(b.z), f2b(b.w)};
  *reinterpret_cast<bf16x8*>(out + (size_t)i * 8) =
      *reinterpret_cast<bf16x8*>(o);
}

// ---------------------------------------------------------------------------
// Pack W (128x128 f32, row-major fan_in x fan_out) into B-fragment order for
// mfma_f32_32x32x16_bf16: frag index [t][s][lane][i], element =
// W[s*16 + (lane>>5)*8 + i][t*32 + (lane&31)].
// ---------------------------------------------------------------------------
__global__ __launch_bounds__(256) void pack_w_kernel(
    const float* __restrict__ W, unsigned short* __restrict__ Wp) {
  int idx = blockIdx.x * 256 + threadIdx.x;  // 0..2047
  if (idx >= 2048) return;
  const int l = idx & 63;
  const int s = (idx >> 6) & 7;
  const int t = idx >> 9;
  const int n = (t << 5) + (l & 31);
  const int k0 = (s << 4) + ((l >> 5) << 3);
  unsigned short o[8];
#pragma unroll
  for (int i = 0; i < 8; ++i) o[i] = f2b(W[(size_t)(k0 + i) * D + n]);
  *reinterpret_cast<bf16x8*>(Wp + (size_t)idx * 8) =
      *reinterpret_cast<bf16x8*>(o);
}

// ---------------------------------------------------------------------------
// CSR build: histogram -> 2-level exclusive scan -> fill
// ---------------------------------------------------------------------------
__global__ __launch_bounds__(256) void hist_kernel(
    const int* __restrict__ dst, int* __restrict__ cnt, int n_edges) {
  int e = blockIdx.x * 256 + threadIdx.x;
  if (e < n_edges) atomicAdd(&cnt[dst[e]], 1);
}

__global__ __launch_bounds__(256) void scanA_kernel(
    const int* __restrict__ cnt, int* __restrict__ rowptr,
    int* __restrict__ chunkSums, int n) {
  __shared__ int lds[256];
  const int t = threadIdx.x;
  const int idx = blockIdx.x * SCAN_CHUNK + t * 4;
  int4 v = make_int4(0, 0, 0, 0);
  if (idx < n) v = *reinterpret_cast<const int4*>(cnt + idx);
  const int s = v.x + v.y + v.z + v.w;
  lds[t] = s;
  __syncthreads();
#pragma unroll
  for (int off = 1; off < 256; off <<= 1) {
    int p = 0;
    if (t >= off) p = lds[t - off];
    __syncthreads();
    lds[t] += p;
    __syncthreads();
  }
  const int excl = lds[t] - s;
  if (idx < n) {
    int4 o;
    o.x = excl;
    o.y = excl + v.x;
    o.z = o.y + v.y;
    o.w = o.z + v.z;
    *reinterpret_cast<int4*>(rowptr + idx) = o;
  }
  if (t == 255) chunkSums[blockIdx.x] = lds[255];
}

__global__ __launch_bounds__(256) void scanB_kernel(int* __restrict__ chunkSums,
                                                    int n_chunks) {
  __shared__ int lds[256];
  const int t = threadIdx.x;
  const int v = (t < n_chunks) ? chunkSums[t] : 0;
  lds[t] = v;
  __syncthreads();
#pragma unroll
  for (int off = 1; off < 256; off <<= 1) {
    int p = 0;
    if (t >= off) p = lds[t - off];
    __syncthreads();
    lds[t] += p;
    __syncthreads();
  }
  if (t < n_chunks) chunkSums[t] = lds[t] - v;
}

__global__ __launch_bounds__(256) void scanC_kernel(
    int* __restrict__ rowptr, const int* __restrict__ chunkSums,
    int* __restrict__ cursor, int n_nodes, int n_edges) {
  int i = blockIdx.x * 256 + threadIdx.x;
  if (i < n_nodes) {
    int v = rowptr[i] + chunkSums[i / SCAN_CHUNK];
    rowptr[i] = v;
    cursor[i] = v;
  }
  if (i == n_nodes) rowptr[n_nodes] = n_edges;
}

__global__ __launch_bounds__(256) void fill_kernel(
    const int* __restrict__ src, const int* __restrict__ dst,
    int* __restrict__ cursor, int* __restrict__ col, int n_edges) {
  int e = blockIdx.x * 256 + threadIdx.x;
  if (e < n_edges) {
    int d = dst[e];
    int pos = atomicAdd(&cursor[d], 1);
    col[pos] = src[e];
  }
}

// ---------------------------------------------------------------------------
// Gather aggregation (bf16): out[n] = X[n] + sum_{j} X[col[j]]
// 32 lanes/node, 8 B (4 bf16) per lane; f32 accumulate; bf16 RNE store.
// ---------------------------------------------------------------------------
__global__ __launch_bounds__(256) void gather_bf16_kernel(
    const unsigned short* __restrict__ X, const int* __restrict__ rowptr,
    const int* __restrict__ col, unsigned short* __restrict__ out,
    int n_nodes) {
  int g = (blockIdx.x * 256 + threadIdx.x) >> 5;
  if (g >= n_nodes) return;
  const int c = threadIdx.x & 31;
  const uint2* Xv = reinterpret_cast<const uint2*>(X);
  uint2 u = Xv[(size_t)g * 32 + c];  // self term
  float a0 = b2f(u.x << 16), a1 = b2f(u.x & 0xffff0000u);
  float a2 = b2f(u.y << 16), a3 = b2f(u.y & 0xffff0000u);
  const int beg = rowptr[g], end = rowptr[g + 1];
  for (int j = beg; j < end; ++j) {
    const uint2 w = Xv[(size_t)col[j] * 32 + c];
    a0 += b2f(w.x << 16);
    a1 += b2f(w.x & 0xffff0000u);
    a2 += b2f(w.y << 16);
    a3 += b2f(w.y & 0xffff0000u);
  }
  uint2 o;
  o.x = (unsigned int)f2b(a0) | ((unsigned int)f2b(a1) << 16);
  o.y = (unsigned int)f2b(a2) | ((unsigned int)f2b(a3) << 16);
  reinterpret_cast<uint2*>(out)[(size_t)g * 32 + c] = o;
}

// ---------------------------------------------------------------------------
// MFMA MLP: out = [relu](S @ W + b) in bf16, f32 accum.
// Wave computes 32 rows x 128 cols via 4 n-tiles x 8 k-steps of
// mfma_f32_32x32x16_bf16. W fragments staged in LDS (32 KB).
// ---------------------------------------------------------------------------
template <int RELU>
__global__ __launch_bounds__(256) void mlp_mfma_kernel(
    const unsigned short* __restrict__ X, const unsigned short* __restrict__ Wp,
    const float* __restrict__ bias, unsigned short* __restrict__ out,
    int n_strips) {
  __shared__ unsigned short wl[4 * 8 * 64 * 8];  // 16384 bf16 = 32 KB
  for (int i = threadIdx.x * 8; i < 16384; i += 256 * 8) {
    *reinterpret_cast<bf16x8*>(wl + i) =
        *reinterpret_cast<const bf16x8*>(Wp + i);
  }
  __syncthreads();

  const int lane = threadIdx.x & 63;
  const int gwave = blockIdx.x * 4 + (threadIdx.x >> 6);
  const int nwaves = gridDim.x * 4;
  const int colbase = lane & 31;
  const int rowoff = (lane >> 5) * 4;

  for (int strip = gwave; strip < n_strips; strip += nwaves) {
    const unsigned short* xrow =
        X + (size_t)(strip * 32 + (lane & 31)) * D + (lane >> 5) * 8;
    f32x16 acc[4] = {};
#pragma unroll
    for (int s = 0; s < 8; ++s) {
      const bf16x8 a = *reinterpret_cast<const bf16x8*>(xrow + s * 16);
#pragma unroll
      for (int t = 0; t < 4; ++t) {
        const bf16x8 b =
            *reinterpret_cast<const bf16x8*>(wl + ((t * 8 + s) * 64 + lane) * 8);
        acc[t] = __builtin_amdgcn_mfma_f32_32x32x16_bf16(a, b, acc[t], 0, 0, 0);
      }
    }
#pragma unroll
    for (int t = 0; t < 4; ++t) {
      const int c = t * 32 + colbase;
      const float bv = bias[c];
#pragma unroll
      for (int r = 0; r < 16; ++r) {
        const int row = strip * 32 + (r & 3) + 8 * (r >> 2) + rowoff;
        float v = acc[t][r] + bv;
        if (RELU) v = fmaxf(v, 0.0f);
        out[(size_t)row * D + c] = f2b(v);
      }
    }
  }
}

// ---------------------------------------------------------------------------
// Global mean pool (batch sorted): run-length accumulate, atomic flush per run.
// ---------------------------------------------------------------------------
#define POOL_NODES_PER_GROUP 128

__global__ __launch_bounds__(256) void pool_kernel(
    const unsigned short* __restrict__ H, const int* __restrict__ batch,
    float* __restrict__ sums, float* __restrict__ counts, int n_nodes) {
  const int group = (blockIdx.x * 256 + threadIdx.x) >> 5;
  const int lane = threadIdx.x & 31;
  const int n0 = group * POOL_NODES_PER_GROUP;
  if (n0 >= n_nodes) return;
  const int n1 = min(n0 + POOL_NODES_PER_GROUP, n_nodes);
  const uint2* Hv = reinterpret_cast<const uint2*>(H);

  float a0 = 0.f, a1 = 0.f, a2 = 0.f, a3 = 0.f;
  int cur = batch[n0];
  int runlen = 0;
  for (int n = n0; n < n1; ++n) {
    const int g = batch[n];
    if (g != cur) {
      float* p = sums + (size_t)cur * D + lane * 4;
      unsafeAtomicAdd(p + 0, a0);
      unsafeAtomicAdd(p + 1, a1);
      unsafeAtomicAdd(p + 2, a2);
      unsafeAtomicAdd(p + 3, a3);
      if (lane == 0) unsafeAtomicAdd(counts + cur, (float)runlen);
      a0 = a1 = a2 = a3 = 0.f;
      cur = g;
      runlen = 0;
    }
    const uint2 v = Hv[(size_t)n * 32 + lane];
    a0 += b2f(v.x << 16);
    a1 += b2f(v.x & 0xffff0000u);
    a2 += b2f(v.y << 16);
    a3 += b2f(v.y & 0xffff0000u);
    ++runlen;
  }
  float* p = sums + (size_t)cur * D + lane * 4;
  unsafeAtomicAdd(p + 0, a0);
  unsafeAtomicAdd(p + 1, a1);
  unsafeAtomicAdd(p + 2, a2);
  unsafeAtomicAdd(p + 3, a3);
  if (lane == 0) unsafeAtomicAdd(counts + cur, (float)runlen);
}

__global__ __launch_bounds__(256) void pool_norm_kernel(
    float* __restrict__ out, const float* __restrict__ counts, int n) {
  int i = blockIdx.x * 256 + threadIdx.x;
  if (i >= n) return;
  float cnt = counts[i / D];
  out[i] = out[i] / fmaxf(cnt, 1.0f);
}

// ---------------------------------------------------------------------------
extern "C" void kernel_launch(void* const* d_in, const int* in_sizes, int n_in,
                              void* d_out, int out_size, void* d_ws,
                              size_t ws_size, hipStream_t stream) {
  const float* x = (const float*)d_in[0];
  const int* ei = (const int*)d_in[1];
  const int* batch = (const int*)d_in[2];
  const float* W[6] = {(const float*)d_in[3],  (const float*)d_in[5],
                       (const float*)d_in[7],  (const float*)d_in[9],
                       (const float*)d_in[11], (const float*)d_in[13]};
  const float* B[6] = {(const float*)d_in[4],  (const float*)d_in[6],
                       (const float*)d_in[8],  (const float*)d_in[10],
                       (const float*)d_in[12], (const float*)d_in[14]};

  const int n_nodes = in_sizes[2];
  const int n_edges = in_sizes[1] / 2;
  const int n_graphs = out_size / D;
  const int* src = ei;
  const int* dst = ei + n_edges;

  const size_t matB = (size_t)n_nodes * D * sizeof(unsigned short);  // 25.6 MB
  unsigned short* bufA = (unsigned short*)d_ws;
  unsigned short* bufB = (unsigned short*)((char*)d_ws + matB);
  unsigned short* bufC = (unsigned short*)((char*)d_ws + 2 * matB);
  unsigned short* wpack = (unsigned short*)((char*)d_ws + 3 * matB);
  int* rowptr = (int*)((char*)wpack + 6 * 16384 * sizeof(unsigned short));
  int* cursor = rowptr + (n_nodes + 1);
  int* colidx = cursor + n_nodes;
  int* chunkSums = colidx + n_edges;
  float* counts = (float*)(chunkSums + 256);

  const dim3 blk(256);
  const int edge_blocks = (n_edges + 255) / 256;
  const int n_chunks = (n_nodes + SCAN_CHUNK - 1) / SCAN_CHUNK;
  const int gather_blocks = (int)(((long long)n_nodes * 32 + 255) / 256);
  const int pool_groups =
      (n_nodes + POOL_NODES_PER_GROUP - 1) / POOL_NODES_PER_GROUP;
  const int pool_blocks = (pool_groups * 32 + 255) / 256;
  const int n_strips = n_nodes / 32;  // 100000 % 32 == 0
  const int mlp_grid = 512;

  // ---- precompute: convert x, pack weights, build CSR ----
  convert_kernel<<<(n_nodes * (D / 8) + 255) / 256, blk, 0, stream>>>(
      x, bufA, n_nodes * (D / 8));
  for (int m = 0; m < 6; ++m)
    pack_w_kernel<<<8, blk, 0, stream>>>(W[m], wpack + (size_t)m * 16384);

  hipMemsetAsync(cursor, 0, (size_t)n_nodes * sizeof(int), stream);
  hist_kernel<<<edge_blocks, blk, 0, stream>>>(dst, cursor, n_edges);
  scanA_kernel<<<n_chunks, blk, 0, stream>>>(cursor, rowptr, chunkSums,
                                             n_nodes);
  scanB_kernel<<<1, blk, 0, stream>>>(chunkSums, n_chunks);
  scanC_kernel<<<(n_nodes + 256) / 256, blk, 0, stream>>>(
      rowptr, chunkSums, cursor, n_nodes, n_edges);
  fill_kernel<<<edge_blocks, blk, 0, stream>>>(src, dst, cursor, colidx,
                                               n_edges);

  // ---- layer 1 ----
  gather_bf16_kernel<<<gather_blocks, blk, 0, stream>>>(bufA, rowptr, colidx,
                                                        bufB, n_nodes);
  mlp_mfma_kernel<1><<<mlp_grid, blk, 0, stream>>>(bufB, wpack + 0 * 16384,
                                                   B[0], bufC, n_strips);
  mlp_mfma_kernel<1><<<mlp_grid, blk, 0, stream>>>(bufC, wpack + 1 * 16384,
                                                   B[1], bufB, n_strips);
  // ---- layer 2 ----
  gather_bf16_kernel<<<gather_blocks, blk, 0, stream>>>(bufB, rowptr, colidx,
                                                        bufC, n_nodes);
  mlp_mfma_kernel<1><<<mlp_grid, blk, 0, stream>>>(bufC, wpack + 2 * 16384,
                                                   B[2], bufA, n_strips);
  mlp_mfma_kernel<1><<<mlp_grid, blk, 0, stream>>>(bufA, wpack + 3 * 16384,
                                                   B[3], bufC, n_strips);
  // ---- layer 3 ----
  gather_bf16_kernel<<<gather_blocks, blk, 0, stream>>>(bufC, rowptr, colidx,
                                                        bufA, n_nodes);
  mlp_mfma_kernel<1><<<mlp_grid, blk, 0, stream>>>(bufA, wpack + 4 * 16384,
                                                   B[4], bufB, n_strips);
  mlp_mfma_kernel<0><<<mlp_grid, blk, 0, stream>>>(bufB, wpack + 5 * 16384,
                                                   B[5], bufA, n_strips);

  // ---- global mean pool ----
  hipMemsetAsync(d_out, 0, (size_t)out_size * sizeof(float), stream);
  hipMemsetAsync(counts, 0, (size_t)n_graphs * sizeof(float), stream);
  pool_kernel<<<pool_blocks, blk, 0, stream>>>(bufA, batch, (float*)d_out,
                                               counts, n_nodes);
  pool_norm_kernel<<<(out_size + 255) / 256, blk, 0, stream>>>((float*)d_out,
                                                               counts,
                                                               out_size);
}

// Round 4
// 544.665 us; speedup vs baseline: 17.2552x; 1.2204x over previous
//
#include <hip/hip_runtime.h>

#define D 128
#define SCAN_CHUNK 1024
#define FILL_EPB 2048

typedef __attribute__((ext_vector_type(8))) short bf16x8;
typedef __attribute__((ext_vector_type(16))) float f32x16;

__device__ inline float b2f(unsigned int hi16_as_lo) {
  union { unsigned int u; float f; } v;
  v.u = hi16_as_lo;
  return v.f;
}
__device__ inline unsigned short f2b(float f) {  // RNE f32 -> bf16
  union { float f; unsigned int u; } v;
  v.f = f;
  unsigned int r = v.u + 0x7FFFu + ((v.u >> 16) & 1u);
  return (unsigned short)(r >> 16);
}
__device__ inline unsigned int pk2(float lo, float hi) {
  return (unsigned int)f2b(lo) | ((unsigned int)f2b(hi) << 16);
}

// ---------------------------------------------------------------------------
// f32 -> bf16 convert (8 elems/thread)
// ---------------------------------------------------------------------------
__global__ __launch_bounds__(256) void convert_kernel(
    const float* __restrict__ in, unsigned short* __restrict__ out, int n8) {
  int i = blockIdx.x * 256 + threadIdx.x;
  if (i >= n8) return;
  const float4 a = *reinterpret_cast<const float4*>(in + (size_t)i * 8);
  const float4 b = *reinterpret_cast<const float4*>(in + (size_t)i * 8 + 4);
  unsigned short o[8] = {f2b(a.x), f2b(a.y), f2b(a.z), f2b(a.w),
                         f2b(b.x), f2b(b.y), f2b(b.z), f2b(b.w)};
  *reinterpret_cast<bf16x8*>(out + (size_t)i * 8) =
      *reinterpret_cast<bf16x8*>(o);
}

// ---------------------------------------------------------------------------
// Pack W (128x128 f32, row-major fan_in x fan_out): lane l, tile t, step s
// holds W[s*16 + (l>>5)*8 + i][t*32 + (l&31)]  == A-frag of W^T (also B-frag
// of W) for mfma_f32_32x32x16_bf16.
// ---------------------------------------------------------------------------
__global__ __launch_bounds__(256) void pack_w_kernel(
    const float* __restrict__ W, unsigned short* __restrict__ Wp) {
  int idx = blockIdx.x * 256 + threadIdx.x;  // 0..2047
  if (idx >= 2048) return;
  const int l = idx & 63;
  const int s = (idx >> 6) & 7;
  const int t = idx >> 9;
  const int n = (t << 5) + (l & 31);
  const int k0 = (s << 4) + ((l >> 5) << 3);
  unsigned short o[8];
#pragma unroll
  for (int i = 0; i < 8; ++i) o[i] = f2b(W[(size_t)(k0 + i) * D + n]);
  *reinterpret_cast<bf16x8*>(Wp + (size_t)idx * 8) =
      *reinterpret_cast<bf16x8*>(o);
}

// ---------------------------------------------------------------------------
// CSR build: histogram -> 2-level exclusive scan -> partitioned fill
// ---------------------------------------------------------------------------
__global__ __launch_bounds__(256) void hist_kernel(
    const int* __restrict__ dst, int* __restrict__ cnt, int n_edges) {
  int e = blockIdx.x * 256 + threadIdx.x;
  if (e < n_edges) atomicAdd(&cnt[dst[e]], 1);
}

__global__ __launch_bounds__(256) void scanA_kernel(
    const int* __restrict__ cnt, int* __restrict__ rowptr,
    int* __restrict__ chunkSums, int n) {
  __shared__ int lds[256];
  const int t = threadIdx.x;
  const int idx = blockIdx.x * SCAN_CHUNK + t * 4;
  int4 v = make_int4(0, 0, 0, 0);
  if (idx < n) v = *reinterpret_cast<const int4*>(cnt + idx);
  const int s = v.x + v.y + v.z + v.w;
  lds[t] = s;
  __syncthreads();
#pragma unroll
  for (int off = 1; off < 256; off <<= 1) {
    int p = 0;
    if (t >= off) p = lds[t - off];
    __syncthreads();
    lds[t] += p;
    __syncthreads();
  }
  const int excl = lds[t] - s;
  if (idx < n) {
    int4 o;
    o.x = excl;
    o.y = excl + v.x;
    o.z = o.y + v.y;
    o.w = o.z + v.z;
    *reinterpret_cast<int4*>(rowptr + idx) = o;
  }
  if (t == 255) chunkSums[blockIdx.x] = lds[255];
}

__global__ __launch_bounds__(256) void scanB_kernel(int* __restrict__ chunkSums,
                                                    int n_chunks) {
  __shared__ int lds[256];
  const int t = threadIdx.x;
  const int v = (t < n_chunks) ? chunkSums[t] : 0;
  lds[t] = v;
  __syncthreads();
#pragma unroll
  for (int off = 1; off < 256; off <<= 1) {
    int p = 0;
    if (t >= off) p = lds[t - off];
    __syncthreads();
    lds[t] += p;
    __syncthreads();
  }
  if (t < n_chunks) chunkSums[t] = lds[t] - v;
}

__global__ __launch_bounds__(256) void scanC_kernel(
    int* __restrict__ rowptr, const int* __restrict__ chunkSums,
    int* __restrict__ cursor, int n_nodes, int n_edges) {
  int i = blockIdx.x * 256 + threadIdx.x;
  if (i < n_nodes) {
    int v = rowptr[i] + chunkSums[i / SCAN_CHUNK];
    rowptr[i] = v;
    cursor[i] = v;
  }
  if (i == n_nodes) rowptr[n_nodes] = n_edges;
}

// Partitioned fill: partition p = blockIdx&7 (round-robin -> one XCD) only
// writes col positions for its node range -> col lines accumulate in one L2
// and evict once as full lines (kills partial-line write thrash).
__global__ __launch_bounds__(256) void fill_kernel(
    const int* __restrict__ src, const int* __restrict__ dst,
    int* __restrict__ cursor, int* __restrict__ col, int n_edges, int npart) {
  const int p = blockIdx.x & 7;
  const int chunk = blockIdx.x >> 3;
  const int lo = p * npart;
  const int hi = lo + npart;
  const int e1 = min((chunk + 1) * FILL_EPB, n_edges);
  for (int e = chunk * FILL_EPB + threadIdx.x; e < e1; e += 256) {
    const int d = dst[e];
    if (d >= lo && d < hi) {
      const int pos = atomicAdd(&cursor[d], 1);
      col[pos] = src[e];
    }
  }
}

// ---------------------------------------------------------------------------
// Gather aggregation (bf16): out[n] = X[n] + sum_{j} X[col[j]]
// 32 lanes/node, 8 B per lane; unrolled x2 for MLP; f32 accumulate.
// ---------------------------------------------------------------------------
__global__ __launch_bounds__(256) void gather_bf16_kernel(
    const unsigned short* __restrict__ X, const int* __restrict__ rowptr,
    const int* __restrict__ col, unsigned short* __restrict__ out,
    int n_nodes) {
  int g = (blockIdx.x * 256 + threadIdx.x) >> 5;
  if (g >= n_nodes) return;
  const int c = threadIdx.x & 31;
  const uint2* Xv = reinterpret_cast<const uint2*>(X);
  uint2 u = Xv[(size_t)g * 32 + c];  // self term
  float a0 = b2f(u.x << 16), a1 = b2f(u.x & 0xffff0000u);
  float a2 = b2f(u.y << 16), a3 = b2f(u.y & 0xffff0000u);
  const int beg = rowptr[g], end = rowptr[g + 1];
  int j = beg;
  for (; j + 1 < end; j += 2) {
    const int s0 = col[j];
    const int s1 = col[j + 1];
    const uint2 w0 = Xv[(size_t)s0 * 32 + c];
    const uint2 w1 = Xv[(size_t)s1 * 32 + c];
    a0 += b2f(w0.x << 16);
    a1 += b2f(w0.x & 0xffff0000u);
    a2 += b2f(w0.y << 16);
    a3 += b2f(w0.y & 0xffff0000u);
    a0 += b2f(w1.x << 16);
    a1 += b2f(w1.x & 0xffff0000u);
    a2 += b2f(w1.y << 16);
    a3 += b2f(w1.y & 0xffff0000u);
  }
  if (j < end) {
    const uint2 w = Xv[(size_t)col[j] * 32 + c];
    a0 += b2f(w.x << 16);
    a1 += b2f(w.x & 0xffff0000u);
    a2 += b2f(w.y << 16);
    a3 += b2f(w.y & 0xffff0000u);
  }
  uint2 o;
  o.x = pk2(a0, a1);
  o.y = pk2(a2, a3);
  reinterpret_cast<uint2*>(out)[(size_t)g * 32 + c] = o;
}

// ---------------------------------------------------------------------------
// Fused MLP pair: out = [relu]( relu(S@W1+b1) @ W2 + b2 ), bf16 io, f32 acc.
// Both GEMMs in transposed orientation (D^T = Wp @ frag), GEMM1->GEMM2
// handoff and row-major store via in-register cvt-pack + half-wave exchange.
// ---------------------------------------------------------------------------
template <int RELU>
__global__ __launch_bounds__(256) void mlp2_kernel(
    const unsigned short* __restrict__ X, const unsigned short* __restrict__ Wp1,
    const unsigned short* __restrict__ Wp2, const float* __restrict__ bias1,
    const float* __restrict__ bias2, unsigned short* __restrict__ out,
    int n_strips) {
  __shared__ unsigned short wl1[16384];  // 32 KB
  __shared__ unsigned short wl2[16384];  // 32 KB
  __shared__ float bl1[128], bl2[128];
  for (int i = threadIdx.x * 8; i < 16384; i += 256 * 8) {
    *reinterpret_cast<bf16x8*>(wl1 + i) = *reinterpret_cast<const bf16x8*>(Wp1 + i);
    *reinterpret_cast<bf16x8*>(wl2 + i) = *reinterpret_cast<const bf16x8*>(Wp2 + i);
  }
  if (threadIdx.x < 128) {
    bl1[threadIdx.x] = bias1[threadIdx.x];
    bl2[threadIdx.x] = bias2[threadIdx.x];
  }
  __syncthreads();

  const int lx = threadIdx.x & 63;
  const int h = lx >> 5;
  const int nl = lx & 31;  // node-local index
  const int gwave = blockIdx.x * 4 + (threadIdx.x >> 6);
  const int nwaves = gridDim.x * 4;

  for (int strip = gwave; strip < n_strips; strip += nwaves) {
    // ---- load X fragments (B-operand of GEMM1: T^T = W1^T @ X^T) ----
    const unsigned short* xrow = X + (size_t)(strip * 32 + nl) * D + h * 8;
    bf16x8 xf[8];
#pragma unroll
    for (int s = 0; s < 8; ++s)
      xf[s] = *reinterpret_cast<const bf16x8*>(xrow + s * 16);

    // ---- GEMM1: acc1[t1] = T^T tile, init with bias1 ----
    f32x16 acc1[4];
#pragma unroll
    for (int t1 = 0; t1 < 4; ++t1)
#pragma unroll
      for (int r = 0; r < 16; ++r)
        acc1[t1][r] = bl1[32 * t1 + (r & 3) + 8 * (r >> 2) + 4 * h];
#pragma unroll
    for (int s = 0; s < 8; ++s) {
#pragma unroll
      for (int t1 = 0; t1 < 4; ++t1) {
        const bf16x8 wf = *reinterpret_cast<const bf16x8*>(
            wl1 + ((t1 * 8 + s) * 64 + lx) * 8);
        acc1[t1] = __builtin_amdgcn_mfma_f32_32x32x16_bf16(wf, xf[s], acc1[t1],
                                                           0, 0, 0);
      }
    }

    // ---- transform T^T -> A2 frags; GEMM2: acc2[t] = out^T tile ----
    f32x16 acc2[4];
#pragma unroll
    for (int t = 0; t < 4; ++t)
#pragma unroll
      for (int r = 0; r < 16; ++r)
        acc2[t][r] = bl2[32 * t + (r & 3) + 8 * (r >> 2) + 4 * h];
#pragma unroll
    for (int s2 = 0; s2 < 8; ++s2) {
      const int t1 = s2 >> 1;
      const int ro = (s2 & 1) << 3;
      const float g0 = fmaxf(acc1[t1][ro + 0], 0.f);
      const float g1 = fmaxf(acc1[t1][ro + 1], 0.f);
      const float g2 = fmaxf(acc1[t1][ro + 2], 0.f);
      const float g3 = fmaxf(acc1[t1][ro + 3], 0.f);
      const float g4 = fmaxf(acc1[t1][ro + 4], 0.f);
      const float g5 = fmaxf(acc1[t1][ro + 5], 0.f);
      const float g6 = fmaxf(acc1[t1][ro + 6], 0.f);
      const float g7 = fmaxf(acc1[t1][ro + 7], 0.f);
      const unsigned int pA0 = pk2(g0, g1), pA1 = pk2(g2, g3);
      const unsigned int pB0 = pk2(g4, g5), pB1 = pk2(g6, g7);
      const unsigned int sA0 = (unsigned int)__shfl((int)pA0, lx ^ 32, 64);
      const unsigned int sA1 = (unsigned int)__shfl((int)pA1, lx ^ 32, 64);
      const unsigned int sB0 = (unsigned int)__shfl((int)pB0, lx ^ 32, 64);
      const unsigned int sB1 = (unsigned int)__shfl((int)pB1, lx ^ 32, 64);
      union { unsigned int u[4]; bf16x8 v; } fr;
      fr.u[0] = h ? sB0 : pA0;
      fr.u[1] = h ? sB1 : pA1;
      fr.u[2] = h ? pB0 : sA0;
      fr.u[3] = h ? pB1 : sA1;
#pragma unroll
      for (int t = 0; t < 4; ++t) {
        const bf16x8 wf = *reinterpret_cast<const bf16x8*>(
            wl2 + ((t * 8 + s2) * 64 + lx) * 8);
        acc2[t] = __builtin_amdgcn_mfma_f32_32x32x16_bf16(wf, fr.v, acc2[t],
                                                          0, 0, 0);
      }
    }

    // ---- epilogue: transform out^T -> row frags, 16B stores ----
    unsigned short* orow = out + (size_t)(strip * 32 + nl) * D + h * 8;
#pragma unroll
    for (int s = 0; s < 8; ++s) {
      const int t = s >> 1;
      const int ro = (s & 1) << 3;
      float g0 = acc2[t][ro + 0], g1 = acc2[t][ro + 1];
      float g2 = acc2[t][ro + 2], g3 = acc2[t][ro + 3];
      float g4 = acc2[t][ro + 4], g5 = acc2[t][ro + 5];
      float g6 = acc2[t][ro + 6], g7 = acc2[t][ro + 7];
      if (RELU) {
        g0 = fmaxf(g0, 0.f); g1 = fmaxf(g1, 0.f);
        g2 = fmaxf(g2, 0.f); g3 = fmaxf(g3, 0.f);
        g4 = fmaxf(g4, 0.f); g5 = fmaxf(g5, 0.f);
        g6 = fmaxf(g6, 0.f); g7 = fmaxf(g7, 0.f);
      }
      const unsigned int pA0 = pk2(g0, g1), pA1 = pk2(g2, g3);
      const unsigned int pB0 = pk2(g4, g5), pB1 = pk2(g6, g7);
      const unsigned int sA0 = (unsigned int)__shfl((int)pA0, lx ^ 32, 64);
      const unsigned int sA1 = (unsigned int)__shfl((int)pA1, lx ^ 32, 64);
      const unsigned int sB0 = (unsigned int)__shfl((int)pB0, lx ^ 32, 64);
      const unsigned int sB1 = (unsigned int)__shfl((int)pB1, lx ^ 32, 64);
      union { unsigned int u[4]; bf16x8 v; } fr;
      fr.u[0] = h ? sB0 : pA0;
      fr.u[1] = h ? sB1 : pA1;
      fr.u[2] = h ? pB0 : sA0;
      fr.u[3] = h ? pB1 : sA1;
      *reinterpret_cast<bf16x8*>(orow + s * 16) = fr.v;
    }
  }
}

// ---------------------------------------------------------------------------
// Global mean pool (batch sorted): run-length accumulate, atomic flush per run.
// ---------------------------------------------------------------------------
#define POOL_NODES_PER_GROUP 128

__global__ __launch_bounds__(256) void pool_kernel(
    const unsigned short* __restrict__ H, const int* __restrict__ batch,
    float* __restrict__ sums, float* __restrict__ counts, int n_nodes) {
  const int group = (blockIdx.x * 256 + threadIdx.x) >> 5;
  const int lane = threadIdx.x & 31;
  const int n0 = group * POOL_NODES_PER_GROUP;
  if (n0 >= n_nodes) return;
  const int n1 = min(n0 + POOL_NODES_PER_GROUP, n_nodes);
  const uint2* Hv = reinterpret_cast<const uint2*>(H);

  float a0 = 0.f, a1 = 0.f, a2 = 0.f, a3 = 0.f;
  int cur = batch[n0];
  int runlen = 0;
  for (int n = n0; n < n1; ++n) {
    const int g = batch[n];
    if (g != cur) {
      float* p = sums + (size_t)cur * D + lane * 4;
      unsafeAtomicAdd(p + 0, a0);
      unsafeAtomicAdd(p + 1, a1);
      unsafeAtomicAdd(p + 2, a2);
      unsafeAtomicAdd(p + 3, a3);
      if (lane == 0) unsafeAtomicAdd(counts + cur, (float)runlen);
      a0 = a1 = a2 = a3 = 0.f;
      cur = g;
      runlen = 0;
    }
    const uint2 v = Hv[(size_t)n * 32 + lane];
    a0 += b2f(v.x << 16);
    a1 += b2f(v.x & 0xffff0000u);
    a2 += b2f(v.y << 16);
    a3 += b2f(v.y & 0xffff0000u);
    ++runlen;
  }
  float* p = sums + (size_t)cur * D + lane * 4;
  unsafeAtomicAdd(p + 0, a0);
  unsafeAtomicAdd(p + 1, a1);
  unsafeAtomicAdd(p + 2, a2);
  unsafeAtomicAdd(p + 3, a3);
  if (lane == 0) unsafeAtomicAdd(counts + cur, (float)runlen);
}

__global__ __launch_bounds__(256) void pool_norm_kernel(
    float* __restrict__ out, const float* __restrict__ counts, int n) {
  int i = blockIdx.x * 256 + threadIdx.x;
  if (i >= n) return;
  float cnt = counts[i / D];
  out[i] = out[i] / fmaxf(cnt, 1.0f);
}

// ---------------------------------------------------------------------------
extern "C" void kernel_launch(void* const* d_in, const int* in_sizes, int n_in,
                              void* d_out, int out_size, void* d_ws,
                              size_t ws_size, hipStream_t stream) {
  const float* x = (const float*)d_in[0];
  const int* ei = (const int*)d_in[1];
  const int* batch = (const int*)d_in[2];
  const float* W[6] = {(const float*)d_in[3],  (const float*)d_in[5],
                       (const float*)d_in[7],  (const float*)d_in[9],
                       (const float*)d_in[11], (const float*)d_in[13]};
  const float* B[6] = {(const float*)d_in[4],  (const float*)d_in[6],
                       (const float*)d_in[8],  (const float*)d_in[10],
                       (const float*)d_in[12], (const float*)d_in[14]};

  const int n_nodes = in_sizes[2];
  const int n_edges = in_sizes[1] / 2;
  const int n_graphs = out_size / D;
  const int* src = ei;
  const int* dst = ei + n_edges;

  const size_t matB = (size_t)n_nodes * D * sizeof(unsigned short);  // 25.6 MB
  unsigned short* bufA = (unsigned short*)d_ws;
  unsigned short* bufB = (unsigned short*)((char*)d_ws + matB);
  unsigned short* bufC = (unsigned short*)((char*)d_ws + 2 * matB);
  unsigned short* wpack = (unsigned short*)((char*)d_ws + 3 * matB);
  int* rowptr = (int*)((char*)wpack + 6 * 16384 * sizeof(unsigned short));
  int* cursor = rowptr + (n_nodes + 1);
  int* colidx = cursor + n_nodes;
  int* chunkSums = colidx + n_edges;
  float* counts = (float*)(chunkSums + 256);

  const dim3 blk(256);
  const int edge_blocks = (n_edges + 255) / 256;
  const int n_chunks = (n_nodes + SCAN_CHUNK - 1) / SCAN_CHUNK;
  const int gather_blocks = (int)(((long long)n_nodes * 32 + 255) / 256);
  const int pool_groups =
      (n_nodes + POOL_NODES_PER_GROUP - 1) / POOL_NODES_PER_GROUP;
  const int pool_blocks = (pool_groups * 32 + 255) / 256;
  const int n_strips = n_nodes / 32;  // 100000 % 32 == 0
  const int mlp_grid = 512;           // 2 blocks/CU at 64 KB LDS
  const int npart = (n_nodes + 7) / 8;
  const int fill_blocks = ((n_edges + FILL_EPB - 1) / FILL_EPB) * 8;

  // ---- precompute: convert x, pack weights, build CSR ----
  convert_kernel<<<(n_nodes * (D / 8) + 255) / 256, blk, 0, stream>>>(
      x, bufA, n_nodes * (D / 8));
  for (int m = 0; m < 6; ++m)
    pack_w_kernel<<<8, blk, 0, stream>>>(W[m], wpack + (size_t)m * 16384);

  hipMemsetAsync(cursor, 0, (size_t)n_nodes * sizeof(int), stream);
  hist_kernel<<<edge_blocks, blk, 0, stream>>>(dst, cursor, n_edges);
  scanA_kernel<<<n_chunks, blk, 0, stream>>>(cursor, rowptr, chunkSums,
                                             n_nodes);
  scanB_kernel<<<1, blk, 0, stream>>>(chunkSums, n_chunks);
  scanC_kernel<<<(n_nodes + 256) / 256, blk, 0, stream>>>(
      rowptr, chunkSums, cursor, n_nodes, n_edges);
  fill_kernel<<<fill_blocks, blk, 0, stream>>>(src, dst, cursor, colidx,
                                               n_edges, npart);

  // ---- layer 1 ----
  gather_bf16_kernel<<<gather_blocks, blk, 0, stream>>>(bufA, rowptr, colidx,
                                                        bufB, n_nodes);
  mlp2_kernel<1><<<mlp_grid, blk, 0, stream>>>(bufB, wpack + 0 * 16384,
                                               wpack + 1 * 16384, B[0], B[1],
                                               bufC, n_strips);
  // ---- layer 2 ----
  gather_bf16_kernel<<<gather_blocks, blk, 0, stream>>>(bufC, rowptr, colidx,
                                                        bufB, n_nodes);
  mlp2_kernel<1><<<mlp_grid, blk, 0, stream>>>(bufB, wpack + 2 * 16384,
                                               wpack + 3 * 16384, B[2], B[3],
                                               bufA, n_strips);
  // ---- layer 3 ----
  gather_bf16_kernel<<<gather_blocks, blk, 0, stream>>>(bufA, rowptr, colidx,
                                                        bufB, n_nodes);
  mlp2_kernel<0><<<mlp_grid, blk, 0, stream>>>(bufB, wpack + 4 * 16384,
                                               wpack + 5 * 16384, B[4], B[5],
                                               bufC, n_strips);

  // ---- global mean pool ----
  hipMemsetAsync(d_out, 0, (size_t)out_size * sizeof(float), stream);
  hipMemsetAsync(counts, 0, (size_t)n_graphs * sizeof(float), stream);
  pool_kernel<<<pool_blocks, blk, 0, stream>>>(bufC, batch, (float*)d_out,
                                               counts, n_nodes);
  pool_norm_kernel<<<(out_size + 255) / 256, blk, 0, stream>>>((float*)d_out,
                                                               counts,
                                                               out_size);
}

// Round 5
// 477.296 us; speedup vs baseline: 19.6907x; 1.1411x over previous
//
#include <hip/hip_runtime.h>

#define D 128
#define SCAN_CHUNK 1024
#define FILL_EPB 2048

typedef __attribute__((ext_vector_type(8))) short bf16x8;
typedef __attribute__((ext_vector_type(16))) float f32x16;

__device__ inline float b2f(unsigned int hi16_as_lo) {
  union { unsigned int u; float f; } v;
  v.u = hi16_as_lo;
  return v.f;
}
__device__ inline unsigned short f2b(float f) {  // RNE f32 -> bf16
  union { float f; unsigned int u; } v;
  v.f = f;
  unsigned int r = v.u + 0x7FFFu + ((v.u >> 16) & 1u);
  return (unsigned short)(r >> 16);
}
__device__ inline unsigned int pk2(float lo, float hi) {
  return (unsigned int)f2b(lo) | ((unsigned int)f2b(hi) << 16);
}

// ---------------------------------------------------------------------------
// f32 -> bf16 convert (8 elems/thread)
// ---------------------------------------------------------------------------
__global__ __launch_bounds__(256) void convert_kernel(
    const float* __restrict__ in, unsigned short* __restrict__ out, int n8) {
  int i = blockIdx.x * 256 + threadIdx.x;
  if (i >= n8) return;
  const float4 a = *reinterpret_cast<const float4*>(in + (size_t)i * 8);
  const float4 b = *reinterpret_cast<const float4*>(in + (size_t)i * 8 + 4);
  unsigned short o[8] = {f2b(a.x), f2b(a.y), f2b(a.z), f2b(a.w),
                         f2b(b.x), f2b(b.y), f2b(b.z), f2b(b.w)};
  *reinterpret_cast<bf16x8*>(out + (size_t)i * 8) =
      *reinterpret_cast<bf16x8*>(o);
}

// ---------------------------------------------------------------------------
// Pack W (128x128 f32, row-major fan_in x fan_out): lane l, tile t, step s
// holds W[s*16 + (l>>5)*8 + i][t*32 + (l&31)]  == A-frag of W^T (also B-frag
// of W) for mfma_f32_32x32x16_bf16.
// ---------------------------------------------------------------------------
__global__ __launch_bounds__(256) void pack_w_kernel(
    const float* __restrict__ W, unsigned short* __restrict__ Wp) {
  int idx = blockIdx.x * 256 + threadIdx.x;  // 0..2047
  if (idx >= 2048) return;
  const int l = idx & 63;
  const int s = (idx >> 6) & 7;
  const int t = idx >> 9;
  const int n = (t << 5) + (l & 31);
  const int k0 = (s << 4) + ((l >> 5) << 3);
  unsigned short o[8];
#pragma unroll
  for (int i = 0; i < 8; ++i) o[i] = f2b(W[(size_t)(k0 + i) * D + n]);
  *reinterpret_cast<bf16x8*>(Wp + (size_t)idx * 8) =
      *reinterpret_cast<bf16x8*>(o);
}

// ---------------------------------------------------------------------------
// CSR build: histogram (+rank capture) -> 2-level scan -> atomic-free fill
// ---------------------------------------------------------------------------
__global__ __launch_bounds__(256) void hist_kernel(
    const int* __restrict__ dst, int* __restrict__ cnt,
    unsigned short* __restrict__ rank, int n_edges) {
  int e = blockIdx.x * 256 + threadIdx.x;
  if (e < n_edges) rank[e] = (unsigned short)atomicAdd(&cnt[dst[e]], 1);
}

__global__ __launch_bounds__(256) void scanA_kernel(
    const int* __restrict__ cnt, int* __restrict__ rowptr,
    int* __restrict__ chunkSums, int n) {
  __shared__ int lds[256];
  const int t = threadIdx.x;
  const int idx = blockIdx.x * SCAN_CHUNK + t * 4;
  int4 v = make_int4(0, 0, 0, 0);
  if (idx < n) v = *reinterpret_cast<const int4*>(cnt + idx);
  const int s = v.x + v.y + v.z + v.w;
  lds[t] = s;
  __syncthreads();
#pragma unroll
  for (int off = 1; off < 256; off <<= 1) {
    int p = 0;
    if (t >= off) p = lds[t - off];
    __syncthreads();
    lds[t] += p;
    __syncthreads();
  }
  const int excl = lds[t] - s;
  if (idx < n) {
    int4 o;
    o.x = excl;
    o.y = excl + v.x;
    o.z = o.y + v.y;
    o.w = o.z + v.z;
    *reinterpret_cast<int4*>(rowptr + idx) = o;
  }
  if (t == 255) chunkSums[blockIdx.x] = lds[255];
}

__global__ __launch_bounds__(256) void scanB_kernel(int* __restrict__ chunkSums,
                                                    int n_chunks) {
  __shared__ int lds[256];
  const int t = threadIdx.x;
  const int v = (t < n_chunks) ? chunkSums[t] : 0;
  lds[t] = v;
  __syncthreads();
#pragma unroll
  for (int off = 1; off < 256; off <<= 1) {
    int p = 0;
    if (t >= off) p = lds[t - off];
    __syncthreads();
    lds[t] += p;
    __syncthreads();
  }
  if (t < n_chunks) chunkSums[t] = lds[t] - v;
}

__global__ __launch_bounds__(256) void scanC_kernel(
    int* __restrict__ rowptr, const int* __restrict__ chunkSums, int n_nodes,
    int n_edges) {
  int i = blockIdx.x * 256 + threadIdx.x;
  if (i < n_nodes) rowptr[i] += chunkSums[i / SCAN_CHUNK];
  if (i == n_nodes) rowptr[n_nodes] = n_edges;
}

// Atomic-free partitioned fill: pos = rowptr[dst] + rank (precomputed in
// hist). Partition p=blockIdx&7 (round-robin -> one XCD) writes only its
// 1/8 node range -> col lines accumulate in that XCD's L2, evict once full.
__global__ __launch_bounds__(256) void fill_kernel(
    const int* __restrict__ src, const int* __restrict__ dst,
    const unsigned short* __restrict__ rank, const int* __restrict__ rowptr,
    int* __restrict__ col, int n_edges, int npart) {
  const int p = blockIdx.x & 7;
  const int chunk = blockIdx.x >> 3;
  const int lo = p * npart;
  const int hi = lo + npart;
  const int e1 = min((chunk + 1) * FILL_EPB, n_edges);
  for (int e = chunk * FILL_EPB + threadIdx.x; e < e1; e += 256) {
    const int d = dst[e];
    if (d >= lo && d < hi) col[rowptr[d] + (int)rank[e]] = src[e];
  }
}

// ---------------------------------------------------------------------------
// Gather aggregation (bf16): out[n] = X[n] + sum_{j} X[col[j]]
// 32 lanes/node, 8 B per lane; unrolled x4 for MLP; f32 accumulate.
// ---------------------------------------------------------------------------
__global__ __launch_bounds__(256) void gather_bf16_kernel(
    const unsigned short* __restrict__ X, const int* __restrict__ rowptr,
    const int* __restrict__ col, unsigned short* __restrict__ out,
    int n_nodes) {
  int g = (blockIdx.x * 256 + threadIdx.x) >> 5;
  if (g >= n_nodes) return;
  const int c = threadIdx.x & 31;
  const uint2* Xv = reinterpret_cast<const uint2*>(X);
  uint2 u = Xv[(size_t)g * 32 + c];  // self term
  float a0 = b2f(u.x << 16), a1 = b2f(u.x & 0xffff0000u);
  float a2 = b2f(u.y << 16), a3 = b2f(u.y & 0xffff0000u);
  const int beg = rowptr[g], end = rowptr[g + 1];
  int j = beg;
  for (; j + 4 <= end; j += 4) {
    const int s0 = col[j + 0];
    const int s1 = col[j + 1];
    const int s2 = col[j + 2];
    const int s3 = col[j + 3];
    const uint2 w0 = Xv[(size_t)s0 * 32 + c];
    const uint2 w1 = Xv[(size_t)s1 * 32 + c];
    const uint2 w2 = Xv[(size_t)s2 * 32 + c];
    const uint2 w3 = Xv[(size_t)s3 * 32 + c];
    a0 += b2f(w0.x << 16); a1 += b2f(w0.x & 0xffff0000u);
    a2 += b2f(w0.y << 16); a3 += b2f(w0.y & 0xffff0000u);
    a0 += b2f(w1.x << 16); a1 += b2f(w1.x & 0xffff0000u);
    a2 += b2f(w1.y << 16); a3 += b2f(w1.y & 0xffff0000u);
    a0 += b2f(w2.x << 16); a1 += b2f(w2.x & 0xffff0000u);
    a2 += b2f(w2.y << 16); a3 += b2f(w2.y & 0xffff0000u);
    a0 += b2f(w3.x << 16); a1 += b2f(w3.x & 0xffff0000u);
    a2 += b2f(w3.y << 16); a3 += b2f(w3.y & 0xffff0000u);
  }
  for (; j < end; ++j) {
    const uint2 w = Xv[(size_t)col[j] * 32 + c];
    a0 += b2f(w.x << 16); a1 += b2f(w.x & 0xffff0000u);
    a2 += b2f(w.y << 16); a3 += b2f(w.y & 0xffff0000u);
  }
  uint2 o;
  o.x = pk2(a0, a1);
  o.y = pk2(a2, a3);
  reinterpret_cast<uint2*>(out)[(size_t)g * 32 + c] = o;
}

// ---------------------------------------------------------------------------
// Fused MLP pair: out = [relu]( relu(S@W1+b1) @ W2 + b2 ), bf16 io, f32 acc.
// Both GEMMs in transposed orientation (D^T = Wp @ frag), GEMM1->GEMM2
// handoff and row-major store via in-register cvt-pack + half-wave exchange.
// ---------------------------------------------------------------------------
template <int RELU>
__global__ __launch_bounds__(256) void mlp2_kernel(
    const unsigned short* __restrict__ X, const unsigned short* __restrict__ Wp1,
    const unsigned short* __restrict__ Wp2, const float* __restrict__ bias1,
    const float* __restrict__ bias2, unsigned short* __restrict__ out,
    int n_strips) {
  __shared__ unsigned short wl1[16384];  // 32 KB
  __shared__ unsigned short wl2[16384];  // 32 KB
  __shared__ float bl1[128], bl2[128];
  for (int i = threadIdx.x * 8; i < 16384; i += 256 * 8) {
    *reinterpret_cast<bf16x8*>(wl1 + i) = *reinterpret_cast<const bf16x8*>(Wp1 + i);
    *reinterpret_cast<bf16x8*>(wl2 + i) = *reinterpret_cast<const bf16x8*>(Wp2 + i);
  }
  if (threadIdx.x < 128) {
    bl1[threadIdx.x] = bias1[threadIdx.x];
    bl2[threadIdx.x] = bias2[threadIdx.x];
  }
  __syncthreads();

  const int lx = threadIdx.x & 63;
  const int h = lx >> 5;
  const int nl = lx & 31;  // node-local index
  const int gwave = blockIdx.x * 4 + (threadIdx.x >> 6);
  const int nwaves = gridDim.x * 4;

  for (int strip = gwave; strip < n_strips; strip += nwaves) {
    // ---- load X fragments (B-operand of GEMM1: T^T = W1^T @ X^T) ----
    const unsigned short* xrow = X + (size_t)(strip * 32 + nl) * D + h * 8;
    bf16x8 xf[8];
#pragma unroll
    for (int s = 0; s < 8; ++s)
      xf[s] = *reinterpret_cast<const bf16x8*>(xrow + s * 16);

    // ---- GEMM1: acc1[t1] = T^T tile, init with bias1 ----
    f32x16 acc1[4];
#pragma unroll
    for (int t1 = 0; t1 < 4; ++t1)
#pragma unroll
      for (int r = 0; r < 16; ++r)
        acc1[t1][r] = bl1[32 * t1 + (r & 3) + 8 * (r >> 2) + 4 * h];
#pragma unroll
    for (int s = 0; s < 8; ++s) {
#pragma unroll
      for (int t1 = 0; t1 < 4; ++t1) {
        const bf16x8 wf = *reinterpret_cast<const bf16x8*>(
            wl1 + ((t1 * 8 + s) * 64 + lx) * 8);
        acc1[t1] = __builtin_amdgcn_mfma_f32_32x32x16_bf16(wf, xf[s], acc1[t1],
                                                           0, 0, 0);
      }
    }

    // ---- transform T^T -> A2 frags; GEMM2: acc2[t] = out^T tile ----
    f32x16 acc2[4];
#pragma unroll
    for (int t = 0; t < 4; ++t)
#pragma unroll
      for (int r = 0; r < 16; ++r)
        acc2[t][r] = bl2[32 * t + (r & 3) + 8 * (r >> 2) + 4 * h];
#pragma unroll
    for (int s2 = 0; s2 < 8; ++s2) {
      const int t1 = s2 >> 1;
      const int ro = (s2 & 1) << 3;
      const float g0 = fmaxf(acc1[t1][ro + 0], 0.f);
      const float g1 = fmaxf(acc1[t1][ro + 1], 0.f);
      const float g2 = fmaxf(acc1[t1][ro + 2], 0.f);
      const float g3 = fmaxf(acc1[t1][ro + 3], 0.f);
      const float g4 = fmaxf(acc1[t1][ro + 4], 0.f);
      const float g5 = fmaxf(acc1[t1][ro + 5], 0.f);
      const float g6 = fmaxf(acc1[t1][ro + 6], 0.f);
      const float g7 = fmaxf(acc1[t1][ro + 7], 0.f);
      const unsigned int pA0 = pk2(g0, g1), pA1 = pk2(g2, g3);
      const unsigned int pB0 = pk2(g4, g5), pB1 = pk2(g6, g7);
      const unsigned int sA0 = (unsigned int)__shfl((int)pA0, lx ^ 32, 64);
      const unsigned int sA1 = (unsigned int)__shfl((int)pA1, lx ^ 32, 64);
      const unsigned int sB0 = (unsigned int)__shfl((int)pB0, lx ^ 32, 64);
      const unsigned int sB1 = (unsigned int)__shfl((int)pB1, lx ^ 32, 64);
      union { unsigned int u[4]; bf16x8 v; } fr;
      fr.u[0] = h ? sB0 : pA0;
      fr.u[1] = h ? sB1 : pA1;
      fr.u[2] = h ? pB0 : sA0;
      fr.u[3] = h ? pB1 : sA1;
#pragma unroll
      for (int t = 0; t < 4; ++t) {
        const bf16x8 wf = *reinterpret_cast<const bf16x8*>(
            wl2 + ((t * 8 + s2) * 64 + lx) * 8);
        acc2[t] = __builtin_amdgcn_mfma_f32_32x32x16_bf16(wf, fr.v, acc2[t],
                                                          0, 0, 0);
      }
    }

    // ---- epilogue: transform out^T -> row frags, 16B stores ----
    unsigned short* orow = out + (size_t)(strip * 32 + nl) * D + h * 8;
#pragma unroll
    for (int s = 0; s < 8; ++s) {
      const int t = s >> 1;
      const int ro = (s & 1) << 3;
      float g0 = acc2[t][ro + 0], g1 = acc2[t][ro + 1];
      float g2 = acc2[t][ro + 2], g3 = acc2[t][ro + 3];
      float g4 = acc2[t][ro + 4], g5 = acc2[t][ro + 5];
      float g6 = acc2[t][ro + 6], g7 = acc2[t][ro + 7];
      if (RELU) {
        g0 = fmaxf(g0, 0.f); g1 = fmaxf(g1, 0.f);
        g2 = fmaxf(g2, 0.f); g3 = fmaxf(g3, 0.f);
        g4 = fmaxf(g4, 0.f); g5 = fmaxf(g5, 0.f);
        g6 = fmaxf(g6, 0.f); g7 = fmaxf(g7, 0.f);
      }
      const unsigned int pA0 = pk2(g0, g1), pA1 = pk2(g2, g3);
      const unsigned int pB0 = pk2(g4, g5), pB1 = pk2(g6, g7);
      const unsigned int sA0 = (unsigned int)__shfl((int)pA0, lx ^ 32, 64);
      const unsigned int sA1 = (unsigned int)__shfl((int)pA1, lx ^ 32, 64);
      const unsigned int sB0 = (unsigned int)__shfl((int)pB0, lx ^ 32, 64);
      const unsigned int sB1 = (unsigned int)__shfl((int)pB1, lx ^ 32, 64);
      union { unsigned int u[4]; bf16x8 v; } fr;
      fr.u[0] = h ? sB0 : pA0;
      fr.u[1] = h ? sB1 : pA1;
      fr.u[2] = h ? pB0 : sA0;
      fr.u[3] = h ? pB1 : sA1;
      *reinterpret_cast<bf16x8*>(orow + s * 16) = fr.v;
    }
  }
}

// ---------------------------------------------------------------------------
// Global mean pool (batch sorted): run-length accumulate, atomic flush per run.
// ---------------------------------------------------------------------------
#define POOL_NODES_PER_GROUP 128

__global__ __launch_bounds__(256) void pool_kernel(
    const unsigned short* __restrict__ H, const int* __restrict__ batch,
    float* __restrict__ sums, float* __restrict__ counts, int n_nodes) {
  const int group = (blockIdx.x * 256 + threadIdx.x) >> 5;
  const int lane = threadIdx.x & 31;
  const int n0 = group * POOL_NODES_PER_GROUP;
  if (n0 >= n_nodes) return;
  const int n1 = min(n0 + POOL_NODES_PER_GROUP, n_nodes);
  const uint2* Hv = reinterpret_cast<const uint2*>(H);

  float a0 = 0.f, a1 = 0.f, a2 = 0.f, a3 = 0.f;
  int cur = batch[n0];
  int runlen = 0;
  for (int n = n0; n < n1; ++n) {
    const int g = batch[n];
    if (g != cur) {
      float* p = sums + (size_t)cur * D + lane * 4;
      unsafeAtomicAdd(p + 0, a0);
      unsafeAtomicAdd(p + 1, a1);
      unsafeAtomicAdd(p + 2, a2);
      unsafeAtomicAdd(p + 3, a3);
      if (lane == 0) unsafeAtomicAdd(counts + cur, (float)runlen);
      a0 = a1 = a2 = a3 = 0.f;
      cur = g;
      runlen = 0;
    }
    const uint2 v = Hv[(size_t)n * 32 + lane];
    a0 += b2f(v.x << 16);
    a1 += b2f(v.x & 0xffff0000u);
    a2 += b2f(v.y << 16);
    a3 += b2f(v.y & 0xffff0000u);
    ++runlen;
  }
  float* p = sums + (size_t)cur * D + lane * 4;
  unsafeAtomicAdd(p + 0, a0);
  unsafeAtomicAdd(p + 1, a1);
  unsafeAtomicAdd(p + 2, a2);
  unsafeAtomicAdd(p + 3, a3);
  if (lane == 0) unsafeAtomicAdd(counts + cur, (float)runlen);
}

__global__ __launch_bounds__(256) void pool_norm_kernel(
    float* __restrict__ out, const float* __restrict__ counts, int n) {
  int i = blockIdx.x * 256 + threadIdx.x;
  if (i >= n) return;
  float cnt = counts[i / D];
  out[i] = out[i] / fmaxf(cnt, 1.0f);
}

// ---------------------------------------------------------------------------
extern "C" void kernel_launch(void* const* d_in, const int* in_sizes, int n_in,
                              void* d_out, int out_size, void* d_ws,
                              size_t ws_size, hipStream_t stream) {
  const float* x = (const float*)d_in[0];
  const int* ei = (const int*)d_in[1];
  const int* batch = (const int*)d_in[2];
  const float* W[6] = {(const float*)d_in[3],  (const float*)d_in[5],
                       (const float*)d_in[7],  (const float*)d_in[9],
                       (const float*)d_in[11], (const float*)d_in[13]};
  const float* B[6] = {(const float*)d_in[4],  (const float*)d_in[6],
                       (const float*)d_in[8],  (const float*)d_in[10],
                       (const float*)d_in[12], (const float*)d_in[14]};

  const int n_nodes = in_sizes[2];
  const int n_edges = in_sizes[1] / 2;
  const int n_graphs = out_size / D;
  const int* src = ei;
  const int* dst = ei + n_edges;

  const size_t matB = (size_t)n_nodes * D * sizeof(unsigned short);  // 25.6 MB
  unsigned short* bufA = (unsigned short*)d_ws;
  unsigned short* bufB = (unsigned short*)((char*)d_ws + matB);
  unsigned short* bufC = (unsigned short*)((char*)d_ws + 2 * matB);
  unsigned short* wpack = (unsigned short*)((char*)d_ws + 3 * matB);
  int* rowptr = (int*)((char*)wpack + 6 * 16384 * sizeof(unsigned short));
  int* cnt = rowptr + (n_nodes + 1);
  int* colidx = cnt + n_nodes;
  unsigned short* rank = (unsigned short*)(colidx + n_edges);
  int* chunkSums = (int*)(rank + n_edges);
  float* counts = (float*)(chunkSums + 256);

  const dim3 blk(256);
  const int edge_blocks = (n_edges + 255) / 256;
  const int n_chunks = (n_nodes + SCAN_CHUNK - 1) / SCAN_CHUNK;
  const int gather_blocks = (int)(((long long)n_nodes * 32 + 255) / 256);
  const int pool_groups =
      (n_nodes + POOL_NODES_PER_GROUP - 1) / POOL_NODES_PER_GROUP;
  const int pool_blocks = (pool_groups * 32 + 255) / 256;
  const int n_strips = n_nodes / 32;  // 100000 % 32 == 0
  const int mlp_grid = 512;           // 2 blocks/CU at 64 KB LDS
  const int npart = (n_nodes + 7) / 8;
  const int fill_blocks = ((n_edges + FILL_EPB - 1) / FILL_EPB) * 8;

  // ---- precompute: convert x, pack weights, build CSR ----
  convert_kernel<<<(n_nodes * (D / 8) + 255) / 256, blk, 0, stream>>>(
      x, bufA, n_nodes * (D / 8));
  for (int m = 0; m < 6; ++m)
    pack_w_kernel<<<8, blk, 0, stream>>>(W[m], wpack + (size_t)m * 16384);

  hipMemsetAsync(cnt, 0, (size_t)n_nodes * sizeof(int), stream);
  hist_kernel<<<edge_blocks, blk, 0, stream>>>(dst, cnt, rank, n_edges);
  scanA_kernel<<<n_chunks, blk, 0, stream>>>(cnt, rowptr, chunkSums, n_nodes);
  scanB_kernel<<<1, blk, 0, stream>>>(chunkSums, n_chunks);
  scanC_kernel<<<(n_nodes + 256) / 256, blk, 0, stream>>>(rowptr, chunkSums,
                                                          n_nodes, n_edges);
  fill_kernel<<<fill_blocks, blk, 0, stream>>>(src, dst, rank, rowptr, colidx,
                                               n_edges, npart);

  // ---- layer 1 ----
  gather_bf16_kernel<<<gather_blocks, blk, 0, stream>>>(bufA, rowptr, colidx,
                                                        bufB, n_nodes);
  mlp2_kernel<1><<<mlp_grid, blk, 0, stream>>>(bufB, wpack + 0 * 16384,
                                               wpack + 1 * 16384, B[0], B[1],
                                               bufC, n_strips);
  // ---- layer 2 ----
  gather_bf16_kernel<<<gather_blocks, blk, 0, stream>>>(bufC, rowptr, colidx,
                                                        bufB, n_nodes);
  mlp2_kernel<1><<<mlp_grid, blk, 0, stream>>>(bufB, wpack + 2 * 16384,
                                               wpack + 3 * 16384, B[2], B[3],
                                               bufA, n_strips);
  // ---- layer 3 ----
  gather_bf16_kernel<<<gather_blocks, blk, 0, stream>>>(bufA, rowptr, colidx,
                                                        bufB, n_nodes);
  mlp2_kernel<0><<<mlp_grid, blk, 0, stream>>>(bufB, wpack + 4 * 16384,
                                               wpack + 5 * 16384, B[4], B[5],
                                               bufC, n_strips);

  // ---- global mean pool ----
  hipMemsetAsync(d_out, 0, (size_t)out_size * sizeof(float), stream);
  hipMemsetAsync(counts, 0, (size_t)n_graphs * sizeof(float), stream);
  pool_kernel<<<pool_blocks, blk, 0, stream>>>(bufC, batch, (float*)d_out,
                                               counts, n_nodes);
  pool_norm_kernel<<<(out_size + 255) / 256, blk, 0, stream>>>((float*)d_out,
                                                               counts,
                                                               out_size);
}